// Round 5
// baseline (752.266 us; speedup 1.0000x reference)
//
#include <hip/hip_runtime.h>
#include <hip/hip_bf16.h>
#include <cstdint>
#include <cstddef>

// Problem constants
#define Bq 4
#define Mq 4
#define Lseq 512
#define Dmod 1024
#define Hq 16
#define DHq 64

using bf16 = __bf16;
using bf16x4 = __attribute__((ext_vector_type(4))) __bf16;
using bf16x8 = __attribute__((ext_vector_type(8))) __bf16;
using f32x4 = __attribute__((ext_vector_type(4))) float;

// -------- async global->LDS, 16B per lane (m97 pattern) --------
__device__ __forceinline__ void gld_lds16(const bf16* g, bf16* l) {
  __builtin_amdgcn_global_load_lds(
      (const __attribute__((address_space(1))) void*)g,
      (__attribute__((address_space(3))) void*)l, 16, 0, 0);
}

// =====================================================================
// GEMM core: C[BM,BN] = A[BM,K] * Bt[BN,K]^T, bf16 in, f32 accum.
// BK=32, 256 threads. LDS layout [row][32] contiguous (required by
// global_load_lds lane ordering: dest = wave-uniform base + lane*16B).
// =====================================================================
template <int WAVES_M, int WAVES_N, int WTM, int WTN>
__device__ __forceinline__ void gemm_core(const bf16* __restrict__ A,
                                          const bf16* __restrict__ Bt,
                                          int K, int lda, int ldb,
                                          bf16* As, bf16* Bs,
                                          f32x4 (&acc)[WTM][WTN]) {
  constexpr int BM = WAVES_M * WTM * 16;
  constexpr int BN = WAVES_N * WTN * 16;
  constexpr int IA = BM / 64;
  constexpr int IB = BN / 64;

  const int t = threadIdx.x;
  const int lane = t & 63;
  const int wave = t >> 6;
  const int wm = wave % WAVES_M;
  const int wn = wave / WAVES_M;
  const int r = t >> 2;            // staging row (0..63)
  const int c8 = (t & 3) * 8;      // staging col (bf16 elems)
  const int fr = lane & 15;        // fragment row/col within 16-tile
  const int fk = (lane >> 4) * 8;  // fragment k offset

  const bf16* Ab = A + (size_t)r * lda + c8;
  const bf16* Bb = Bt + (size_t)r * ldb + c8;

  for (int k0 = 0; k0 < K; k0 += 32) {
    if (k0) __syncthreads();  // protect LDS from previous iter's readers
#pragma unroll
    for (int i = 0; i < IA; ++i)
      gld_lds16(Ab + (size_t)i * 64 * lda + k0, As + i * 2048 + t * 8);
#pragma unroll
    for (int i = 0; i < IB; ++i)
      gld_lds16(Bb + (size_t)i * 64 * ldb + k0, Bs + i * 2048 + t * 8);
    asm volatile("s_waitcnt vmcnt(0)" ::: "memory");
    __syncthreads();

    bf16x8 af[WTM], bfv[WTN];
#pragma unroll
    for (int i = 0; i < WTM; ++i)
      af[i] = *(const bf16x8*)(As + (wm * WTM * 16 + i * 16 + fr) * 32 + fk);
#pragma unroll
    for (int j = 0; j < WTN; ++j)
      bfv[j] = *(const bf16x8*)(Bs + (wn * WTN * 16 + j * 16 + fr) * 32 + fk);
#pragma unroll
    for (int i = 0; i < WTM; ++i)
#pragma unroll
      for (int j = 0; j < WTN; ++j)
        acc[i][j] = __builtin_amdgcn_mfma_f32_16x16x32_bf16(af[i], bfv[j],
                                                            acc[i][j], 0, 0, 0);
  }
}

// -------- plain 128x128 GEMM: C = A * Bt^T (bf16 store) --------
__global__ __launch_bounds__(256) void gemm_bt_128(
    const bf16* __restrict__ A, const bf16* __restrict__ Bt,
    bf16* __restrict__ C, int K, int lda, int ldb, int ldc) {
  __shared__ __align__(16) bf16 As[128 * 32];
  __shared__ __align__(16) bf16 Bs[128 * 32];
  f32x4 acc[4][4] = {};
  const bf16* Ab = A + (size_t)blockIdx.y * 128 * lda;
  const bf16* Bb = Bt + (size_t)blockIdx.x * 128 * ldb;
  gemm_core<2, 2, 4, 4>(Ab, Bb, K, lda, ldb, As, Bs, acc);

  const int t = threadIdx.x, lane = t & 63, wave = t >> 6;
  const int wm = wave & 1, wn = wave >> 1;
  const int cr = (lane >> 4) * 4, cc = lane & 15;
  const size_t row0 = (size_t)blockIdx.y * 128 + wm * 64;
  const size_t col0 = (size_t)blockIdx.x * 128 + wn * 64;
#pragma unroll
  for (int i = 0; i < 4; ++i)
#pragma unroll
    for (int j = 0; j < 4; ++j)
#pragma unroll
      for (int rg = 0; rg < 4; ++rg)
        C[(row0 + i * 16 + cr + rg) * ldc + col0 + j * 16 + cc] =
            (bf16)acc[i][j][rg];
}

// -------- final GEMM: C(f32) = A*Bt^T + resid(f32) --------
__global__ __launch_bounds__(256) void gemm_bt_resid(
    const bf16* __restrict__ A, const bf16* __restrict__ Bt,
    const float* __restrict__ resid, float* __restrict__ C, int K, int lda,
    int ldb, int ldc) {
  __shared__ __align__(16) bf16 As[128 * 32];
  __shared__ __align__(16) bf16 Bs[128 * 32];
  f32x4 acc[4][4] = {};
  const bf16* Ab = A + (size_t)blockIdx.y * 128 * lda;
  const bf16* Bb = Bt + (size_t)blockIdx.x * 128 * ldb;
  gemm_core<2, 2, 4, 4>(Ab, Bb, K, lda, ldb, As, Bs, acc);

  const int t = threadIdx.x, lane = t & 63, wave = t >> 6;
  const int wm = wave & 1, wn = wave >> 1;
  const int cr = (lane >> 4) * 4, cc = lane & 15;
  const size_t row0 = (size_t)blockIdx.y * 128 + wm * 64;
  const size_t col0 = (size_t)blockIdx.x * 128 + wn * 64;
#pragma unroll
  for (int i = 0; i < 4; ++i)
#pragma unroll
    for (int j = 0; j < 4; ++j)
#pragma unroll
      for (int rg = 0; rg < 4; ++rg) {
        size_t idx = (row0 + i * 16 + cr + rg) * ldc + col0 + j * 16 + cc;
        C[idx] = acc[i][j][rg] + resid[idx];
      }
}

// -------- scores GEMM: S = qh * qih^T per (b,m,h); epilogue does
// mask + exp(s-1) (fixed shift valid: |cos sim| <= ~1); unnormalized p
// written f32 into the attn output region --------
__global__ __launch_bounds__(256) void gemm_scores(
    const bf16* __restrict__ qh, const bf16* __restrict__ qih,
    const int* __restrict__ mask, float* __restrict__ attn) {
  __shared__ __align__(16) bf16 As[128 * 32];
  __shared__ __align__(16) bf16 Bs[128 * 32];
  f32x4 acc[4][4] = {};
  const int z = blockIdx.z;  // (b*M+m)*H + h
  const int bm = z >> 4, h = z & 15;
  const bf16* Ab = qh + (size_t)bm * Lseq * Dmod + h * DHq +
                   (size_t)blockIdx.y * 128 * Dmod;
  const bf16* Bb = qih + (size_t)bm * Lseq * Dmod + h * DHq +
                   (size_t)blockIdx.x * 128 * Dmod;
  gemm_core<2, 2, 4, 4>(Ab, Bb, DHq, Dmod, Dmod, As, Bs, acc);

  const int* mrow = mask + (size_t)bm * Lseq * Lseq;
  float* crow = attn + (size_t)z * Lseq * Lseq;
  const int t = threadIdx.x, lane = t & 63, wave = t >> 6;
  const int wm = wave & 1, wn = wave >> 1;
  const int cr = (lane >> 4) * 4, cc = lane & 15;
  const int row0 = blockIdx.y * 128 + wm * 64;
  const int col0 = blockIdx.x * 128 + wn * 64;
#pragma unroll
  for (int i = 0; i < 4; ++i)
#pragma unroll
    for (int j = 0; j < 4; ++j)
#pragma unroll
      for (int rg = 0; rg < 4; ++rg) {
        size_t grow = row0 + i * 16 + cr + rg;
        size_t gcol = col0 + j * 16 + cc;
        float v = acc[i][j][rg];
        float o = 0.0f;
        if (mrow[grow * Lseq + gcol] != 0) o = __expf(v - 1.0f);
        crow[grow * Lseq + gcol] = o;
      }
}

// -------- PV GEMM: out_h = attn(f32) * qih (via qih_t as Bt), 128x64 ----
// A staged via registers with f32->bf16 convert; B via global_load_lds.
__global__ __launch_bounds__(256) void gemm_pv(const float* __restrict__ attn,
                                               const bf16* __restrict__ qih_t,
                                               bf16* __restrict__ outh) {
  __shared__ __align__(16) bf16 As[128 * 32];
  __shared__ __align__(16) bf16 Bs[64 * 32];
  f32x4 acc[2][4] = {};
  const int z = blockIdx.z;
  const int bm = z >> 4, h = z & 15;
  const float* Ab =
      attn + (size_t)z * Lseq * Lseq + (size_t)blockIdx.y * 128 * Lseq;
  const bf16* Bb = qih_t + (size_t)z * DHq * Lseq;

  const int t = threadIdx.x;
  const int lane = t & 63;
  const int wave = t >> 6;
  const int ra = t >> 3;           // A staging row base (0..31)
  const int ca = (t & 7) * 4;      // A staging col (f32 elems)
  const int rb = t >> 2;           // B staging row (0..63)
  const int cb = (t & 3) * 8;      // B staging col
  const int fr = lane & 15;
  const int fk = (lane >> 4) * 8;

  for (int k0 = 0; k0 < Lseq; k0 += 32) {
    float4 va[4];
#pragma unroll
    for (int i = 0; i < 4; ++i)
      va[i] = *(const float4*)(Ab + (size_t)(i * 32 + ra) * Lseq + k0 + ca);
    if (k0) __syncthreads();
#pragma unroll
    for (int i = 0; i < 4; ++i) {
      bf16x4 o;
      o[0] = (bf16)va[i].x; o[1] = (bf16)va[i].y;
      o[2] = (bf16)va[i].z; o[3] = (bf16)va[i].w;
      *(bf16x4*)(As + (i * 32 + ra) * 32 + ca) = o;
    }
    gld_lds16(Bb + (size_t)rb * Lseq + k0 + cb, Bs + t * 8);
    asm volatile("s_waitcnt vmcnt(0)" ::: "memory");
    __syncthreads();

    bf16x8 af[2], bfv[4];
#pragma unroll
    for (int i = 0; i < 2; ++i)
      af[i] = *(const bf16x8*)(As + (wave * 32 + i * 16 + fr) * 32 + fk);
#pragma unroll
    for (int j = 0; j < 4; ++j)
      bfv[j] = *(const bf16x8*)(Bs + (j * 16 + fr) * 32 + fk);
#pragma unroll
    for (int i = 0; i < 2; ++i)
#pragma unroll
      for (int j = 0; j < 4; ++j)
        acc[i][j] = __builtin_amdgcn_mfma_f32_16x16x32_bf16(af[i], bfv[j],
                                                            acc[i][j], 0, 0, 0);
  }

  bf16* Cb = outh + (size_t)bm * Lseq * Dmod + h * DHq;
  const int cr = (lane >> 4) * 4, cc = lane & 15;
  const size_t row0 = (size_t)blockIdx.y * 128 + wave * 32;
#pragma unroll
  for (int i = 0; i < 2; ++i)
#pragma unroll
    for (int j = 0; j < 4; ++j)
#pragma unroll
      for (int rg = 0; rg < 4; ++rg)
        Cb[(row0 + i * 16 + cr + rg) * Dmod + j * 16 + cc] =
            (bf16)acc[i][j][rg];
}

// -------- LayerNorm over D=1024, f32 in -> bf16 out, one block/row -------
__global__ __launch_bounds__(256) void ln_kernel(const float* __restrict__ q,
                                                 const float* __restrict__ g,
                                                 const float* __restrict__ b,
                                                 bf16* __restrict__ qn) {
  const size_t row = blockIdx.x;
  const float* x = q + row * Dmod;
  bf16* y = qn + row * Dmod;
  const int t = threadIdx.x;
  float4 v = *(const float4*)(x + t * 4);
  float s = v.x + v.y + v.z + v.w;
  float ss = v.x * v.x + v.y * v.y + v.z * v.z + v.w * v.w;
  for (int off = 32; off; off >>= 1) {
    s += __shfl_xor(s, off);
    ss += __shfl_xor(ss, off);
  }
  __shared__ float sm[8];
  const int wave = t >> 6, lane = t & 63;
  if (lane == 0) { sm[wave * 2] = s; sm[wave * 2 + 1] = ss; }
  __syncthreads();
  s = sm[0] + sm[2] + sm[4] + sm[6];
  ss = sm[1] + sm[3] + sm[5] + sm[7];
  const float mean = s * (1.0f / Dmod);
  const float var = ss * (1.0f / Dmod) - mean * mean;
  const float rstd = rsqrtf(var + 1e-6f);
  float4 gg = *(const float4*)(g + t * 4);
  float4 bb = *(const float4*)(b + t * 4);
  bf16x4 o;
  o[0] = (bf16)((v.x - mean) * rstd * gg.x + bb.x);
  o[1] = (bf16)((v.y - mean) * rstd * gg.y + bb.y);
  o[2] = (bf16)((v.z - mean) * rstd * gg.z + bb.z);
  o[3] = (bf16)((v.w - mean) * rstd * gg.w + bb.w);
  *(bf16x4*)(y + t * 4) = o;
}

// -------- f32 -> bf16 bulk convert (for qi) --------
__global__ __launch_bounds__(256) void cvt_f32_bf16(const float* __restrict__ in,
                                                    bf16* __restrict__ out) {
  const size_t i = ((size_t)blockIdx.x * 256 + threadIdx.x) * 4;
  float4 v = *(const float4*)(in + i);
  bf16x4 o;
  o[0] = (bf16)v.x; o[1] = (bf16)v.y; o[2] = (bf16)v.z; o[3] = (bf16)v.w;
  *(bf16x4*)(out + i) = o;
}

// -------- L2 normalize each contiguous 64-elem chunk (one wave each) ----
__global__ __launch_bounds__(256) void l2norm_kernel(bf16* __restrict__ x) {
  const size_t chunk = (size_t)blockIdx.x * 4 + (threadIdx.x >> 6);
  const int lane = threadIdx.x & 63;
  bf16* p = x + chunk * 64;
  const float v = (float)p[lane];
  float s = v * v;
  for (int off = 32; off; off >>= 1) s += __shfl_xor(s, off);
  const float r = (s > 0.0f) ? rsqrtf(s) : 0.0f;
  p[lane] = (bf16)(v * r);
}

// -------- attn normalization (f32): one block per (b,h,lq) --------------
__global__ __launch_bounds__(256) void attn_norm(float* __restrict__ attn) {
  const int idx = blockIdx.x;
  const int lq = idx & (Lseq - 1);
  const int h = (idx >> 9) & (Hq - 1);
  const int b = idx >> 13;
  const int t = threadIdx.x;
  float4 v[2];
  size_t ad[2];
  float s = 0.0f;
#pragma unroll
  for (int j = 0; j < 2; ++j) {
    const int chunk = t + j * 256;          // 512 float4 chunks = 4m x 128
    const int m = chunk >> 7, lk = (chunk & 127) * 4;
    ad[j] = ((size_t)(((b * Mq + m) * Hq + h) * Lseq + lq)) * Lseq + lk;
    v[j] = *(const float4*)(attn + ad[j]);
    s += v[j].x + v[j].y + v[j].z + v[j].w;
  }
  for (int off = 32; off; off >>= 1) s += __shfl_xor(s, off);
  __shared__ float sm[4];
  const int wave = t >> 6, lane = t & 63;
  if (lane == 0) sm[wave] = s;
  __syncthreads();
  s = sm[0] + sm[1] + sm[2] + sm[3];
  const float inv = (s > 0.0f) ? 1.0f / s : 0.0f;
#pragma unroll
  for (int j = 0; j < 2; ++j) {
    float4 o;
    o.x = v[j].x * inv; o.y = v[j].y * inv;
    o.z = v[j].z * inv; o.w = v[j].w * inv;
    *(float4*)(attn + ad[j]) = o;
  }
}

// -------- 64x64 tiled transpose, f32 in -> bf16 out ------
__global__ __launch_bounds__(256) void transpose64_f32(
    const float* __restrict__ in, bf16* __restrict__ out, int ld_in,
    int ld_out) {
  __shared__ bf16 tile[64 * 65];
  const int r0 = blockIdx.y * 64, c0 = blockIdx.x * 64;
  const int t = threadIdx.x, cl = t & 63, rq = t >> 6;
#pragma unroll
  for (int it = 0; it < 16; ++it) {
    const int rl = it * 4 + rq;
    tile[cl * 65 + rl] = (bf16)in[(size_t)(r0 + rl) * ld_in + c0 + cl];
  }
  __syncthreads();
#pragma unroll
  for (int it = 0; it < 16; ++it) {
    const int ol = it * 4 + rq;
    out[(size_t)(c0 + ol) * ld_out + r0 + cl] = tile[ol * 65 + cl];
  }
}

// -------- per-(b,m,h) transpose of qih [512,64]->[64,512] for PV Bt ------
__global__ __launch_bounds__(256) void transpose_qih(
    const bf16* __restrict__ qih, bf16* __restrict__ qih_t) {
  __shared__ bf16 tile[64 * 65];
  const int z = blockIdx.z;
  const int bm = z >> 4, h = z & 15;
  const bf16* in = qih + (size_t)bm * Lseq * Dmod + h * DHq;  // 512x64 ld 1024
  bf16* out = qih_t + (size_t)z * DHq * Lseq;                 // 64x512 ld 512
  const int r0 = blockIdx.x * 64;  // lk tile
  const int t = threadIdx.x, cl = t & 63, rq = t >> 6;
#pragma unroll
  for (int it = 0; it < 16; ++it) {
    const int rl = it * 4 + rq;
    tile[cl * 65 + rl] = in[(size_t)(r0 + rl) * Dmod + cl];
  }
  __syncthreads();
#pragma unroll
  for (int it = 0; it < 16; ++it) {
    const int dh = it * 4 + rq;
    out[(size_t)dh * Lseq + r0 + cl] = tile[dh * 65 + cl];
  }
}

extern "C" void kernel_launch(void* const* d_in, const int* in_sizes, int n_in,
                              void* d_out, int out_size, void* d_ws,
                              size_t ws_size, hipStream_t stream) {
  // Inputs f32 (reference dtype); outputs f32 (reference output dtype).
  const float* q = (const float*)d_in[0];
  // d_in[1] = k, unused by the reference forward
  const float* qi = (const float*)d_in[2];
  const int* mask = (const int*)d_in[3];
  const float* w_qs = (const float*)d_in[4];
  const float* w_qis = (const float*)d_in[5];
  const float* w_fc = (const float*)d_in[6];
  const float* ln_g = (const float*)d_in[7];
  const float* ln_b = (const float*)d_in[8];

  float* out = (float*)d_out;
  const size_t NE = (size_t)Bq * Mq * Lseq * Dmod;  // 8,388,608
  float* attn = out + NE;  // second tuple element (67,108,864 f32)

  // Scratch parked in the attn output region (dead before gemm_scores):
  char* attnc = (char*)attn;  // 268 MB available
  bf16* qib = (bf16*)attnc;                       // 16 MB
  bf16* wqs_t = (bf16*)(attnc + (16u << 20));     // 2 MB
  bf16* wqis_t = (bf16*)(attnc + (18u << 20));    // 2 MB

  char* ws = (char*)d_ws;
  const size_t SZ = NE * sizeof(bf16);  // 16 MiB
  bf16* qn = (bf16*)(ws);               // LN out; reused as out_h later
  bf16* qh = (bf16*)(ws + SZ);
  bf16* qih = (bf16*)(ws + 2 * SZ);
  bf16* qih_t = (bf16*)(ws + 3 * SZ);
  bf16* wfc_t = (bf16*)(ws + 4 * SZ);   // must survive to the last GEMM
  bf16* outh = qn;                      // qn dead after first projection

  const int ROWS = Bq * Mq * Lseq;  // 8192

  // 1) input conversions / weight transposes (Bt layout for gemm core)
  cvt_f32_bf16<<<NE / 1024, 256, 0, stream>>>(qi, qib);
  transpose64_f32<<<dim3(16, 16), 256, 0, stream>>>(w_qs, wqs_t, Dmod, Dmod);
  transpose64_f32<<<dim3(16, 16), 256, 0, stream>>>(w_qis, wqis_t, Dmod, Dmod);
  transpose64_f32<<<dim3(16, 16), 256, 0, stream>>>(w_fc, wfc_t, Dmod, Dmod);

  // 2) LayerNorm(q) -> qn
  ln_kernel<<<ROWS, 256, 0, stream>>>(q, ln_g, ln_b, qn);

  // 3) projections
  gemm_bt_128<<<dim3(Dmod / 128, ROWS / 128), 256, 0, stream>>>(
      qn, wqs_t, qh, Dmod, Dmod, Dmod, Dmod);
  gemm_bt_128<<<dim3(Dmod / 128, ROWS / 128), 256, 0, stream>>>(
      qib, wqis_t, qih, Dmod, Dmod, Dmod, Dmod);

  // 4) per-head L2 normalize (in place; head chunks are contiguous 64)
  l2norm_kernel<<<ROWS * Hq / 4, 256, 0, stream>>>(qh);
  l2norm_kernel<<<ROWS * Hq / 4, 256, 0, stream>>>(qih);

  // 5) qih^T per (b,m,h) for the PV gemm's Bt operand
  transpose_qih<<<dim3(Lseq / 64, 1, Bq * Mq * Hq), 256, 0, stream>>>(qih,
                                                                      qih_t);

  // 6) scores + mask + exp(s-1) -> unnormalized p (f32) in attn region
  //    (overwrites qib/wqs_t/wqis_t scratch — dead by now)
  gemm_scores<<<dim3(Lseq / 128, Lseq / 128, Bq * Mq * Hq), 256, 0, stream>>>(
      qh, qih, mask, attn);

  // 7) joint (m,lk) softmax denominator + in-place normalize (f32)
  attn_norm<<<Bq * Hq * Lseq, 256, 0, stream>>>(attn);

  // 8) out_h = attn @ qih (A f32->bf16 in staging; into dead qn buf)
  gemm_pv<<<dim3(1, Lseq / 128, Bq * Mq * Hq), 256, 0, stream>>>(attn, qih_t,
                                                                 outh);

  // 9) out = out_h @ w_fc + q (f32 out, f32 residual)
  gemm_bt_resid<<<dim3(Dmod / 128, ROWS / 128), 256, 0, stream>>>(
      outh, wfc_t, q, out, Dmod, Dmod, Dmod, Dmod);
}